// Round 5
// baseline (549.639 us; speedup 1.0000x reference)
//
#include <hip/hip_runtime.h>
#include <hip/hip_bf16.h>
#include <stdint.h>

// MegaNeRF fused MoE-MLP for MI355X (gfx950).  Round 5.
// E=8 experts, MLP 90->256->256->256->4, N=131072 points, inverse-distance gating.
//
// Round-5: evidence says occupancy is set by TOTAL regs (arch+acc) vs 512 pool:
//   r2: 92 total -> 4 waves/SIMD (47%); r3: cap128 w/ demand 192 -> spill;
//   r4: 192 total -> 2 waves/SIMD (24%).
// Fix: evict xf[4][3] (48 VGPRs) by pre-staging X as bf16 A-fragments in d_ws;
// layer-1 A comes from global (L3-resident).  Total ~110 <= 128 under
// launch_bounds(512,4) -> 2 blocks/CU, cross-block barrier overlap.
// Fallback to the round-4 kernel if ws_size is too small for weights+X.

#define NE    8
#define FIN   90
#define HD    256
#define NOUT  4
#define XC    93          // 3 + FIN columns in x

#define MT        128     // points per block
#define NTHREADS  512     // 8 waves: 2 (wr) x 4 (wc)
#define HSTR      264     // LDS h stride (bf16 elems), +8 pad

#define KQ1   3           // ceil(90/32) -> K padded to 96
#define KQH   8           // 256/32
#define NBH   16          // 256/16

#define W1_ELEMS (NE*NBH*KQ1*512)   // 196608
#define W2_ELEMS (NE*NBH*KQH*512)   // 524288
#define WO_ELEMS (NE*KQH*512)       // 32768  (OUT padded 4->16)
#define WTOT     (W1_ELEMS + 2*W2_ELEMS + WO_ELEMS)   // 1277952 elems

typedef __attribute__((ext_vector_type(8))) short bf16x8;
typedef __attribute__((ext_vector_type(4))) float f32x4;

__device__ __forceinline__ unsigned short f2bf(float f) {   // cold path only
  union { float f; uint32_t u; } v; v.f = f;
  v.u += 0x7fffu + ((v.u >> 16) & 1u);   // RNE
  return (unsigned short)(v.u >> 16);
}

// ---------------------------------------------------------------------------
// Weight conversion: f32 [e][k][n] -> bf16 fragments [frag][lane][8] where
// frag = (e*NBH + nb)*KQ + kq, element (lane,j) = W[k = kq*32+(lane>>4)*8+j]
//                                                  [n = nb*16+(lane&15)].
// Exactly the mfma_f32_16x16x32_bf16 B-operand layout: one coalesced 16B/lane.
// ---------------------------------------------------------------------------
__global__ __launch_bounds__(256)
void convert_weights(const float* __restrict__ W1, const float* __restrict__ W2,
                     const float* __restrict__ W3, const float* __restrict__ Wo,
                     unsigned short* __restrict__ ws) {
  int idx = blockIdx.x * 256 + threadIdx.x;
  int j = idx & 7;
  int lane = (idx >> 3) & 63;
  int n16 = lane & 15;
  int kof = ((lane >> 4) << 3) + j;
  if (idx < W1_ELEMS) {
    int f = idx >> 9;
    int kq = f % KQ1; f /= KQ1;
    int nb = f % NBH; int e = f / NBH;
    int n = nb*16 + n16, k = kq*32 + kof;
    float v = (k < FIN) ? W1[(e*FIN + k)*HD + n] : 0.f;
    ws[idx] = f2bf(v);
  } else if (idx < W1_ELEMS + 2*W2_ELEMS) {
    int t = idx - W1_ELEMS;
    const float* W = (t < W2_ELEMS) ? W2 : W3;
    int u = (t < W2_ELEMS) ? t : (t - W2_ELEMS);
    int f = u >> 9;
    int kq = f % KQH; f /= KQH;
    int nb = f % NBH; int e = f / NBH;
    int n = nb*16 + n16, k = kq*32 + kof;
    ws[idx] = f2bf(W[(e*HD + k)*HD + n]);
  } else if (idx < WTOT) {
    int t = idx - (W1_ELEMS + 2*W2_ELEMS);
    int f = t >> 9;
    int kq = f % KQH; int e = f / KQH;
    int k = kq*32 + kof;
    float v = (n16 < NOUT) ? Wo[(e*HD + k)*NOUT + n16] : 0.f;
    ws[idx] = f2bf(v);
  }
}

// ---------------------------------------------------------------------------
// X conversion: f32 x[:,3:] -> bf16 A-fragments.  frag f = r16*KQ1 + kq,
// element (lane,j) = X[row = r16*16 + (lane&15)][k = kq*32+(lane>>4)*8+j]
// (0 beyond FIN).  Fused layer-1 loads a[mf] with one 16B read per lane.
// ---------------------------------------------------------------------------
__global__ __launch_bounds__(256)
void convert_x(const float* __restrict__ x, unsigned short* __restrict__ xs, int nfrag) {
  int idx = blockIdx.x * 256 + threadIdx.x;
  if (idx >= nfrag * 512) return;
  int j = idx & 7;
  int lane = (idx >> 3) & 63;
  int f = idx >> 9;
  int kq = f % KQ1;
  int r16 = f / KQ1;
  int row = r16*16 + (lane & 15);
  int k = kq*32 + ((lane >> 4) << 3) + j;
  float v = (k < FIN) ? x[(size_t)row*XC + 3 + k] : 0.f;
  xs[idx] = f2bf(v);
}

// Epilogue: relu + f32->bf16 (HW cvt), scatter C fragments into LDS h buffer.
// C/D layout (verified m89): col = lane&15, row = (lane>>4)*4 + reg.
__device__ __forceinline__ void store_h(f32x4 (&acc)[4][4], unsigned short* hout,
                                        int wr, int wc, int l15, int l4) {
#pragma unroll
  for (int nf = 0; nf < 4; ++nf) {
    int col = wc*64 + nf*16 + l15;
#pragma unroll
    for (int mf = 0; mf < 4; ++mf) {
      int row = wr*64 + mf*16 + l4*4;
#pragma unroll
      for (int j = 0; j < 4; ++j)
        *reinterpret_cast<__hip_bfloat16*>(&hout[(row + j)*HSTR + col]) =
            __float2bfloat16(fmaxf(acc[mf][nf][j], 0.f));
    }
  }
}

// One hidden layer IN PLACE: h(128x256 bf16 LDS) @ W + b -> relu -> h.
__device__ __forceinline__ void layerH(unsigned short* h,
                                       const unsigned short* __restrict__ fw,
                                       const float* __restrict__ bias,
                                       int wr, int wc, int l15, int l4, int lane) {
  f32x4 acc[4][4];
#pragma unroll
  for (int nf = 0; nf < 4; ++nf) {
    float bv = bias[wc*64 + nf*16 + l15];      // bias folded into acc init
#pragma unroll
    for (int mf = 0; mf < 4; ++mf)
      acc[mf][nf] = f32x4{bv, bv, bv, bv};
  }

#pragma unroll
  for (int kq = 0; kq < KQH; ++kq) {
    bf16x8 a[4];
#pragma unroll
    for (int mf = 0; mf < 4; ++mf)
      a[mf] = *(const bf16x8*)(h + (wr*64 + mf*16 + l15)*HSTR + kq*32 + l4*8);
    const unsigned short* bp = fw + ((((wc*4)*KQH) + kq) << 9) + lane*8;
#pragma unroll
    for (int nf = 0; nf < 4; ++nf) {
      bf16x8 b = *(const bf16x8*)(bp + ((nf*KQH) << 9));
#pragma unroll
      for (int mf = 0; mf < 4; ++mf)
        acc[mf][nf] = __builtin_amdgcn_mfma_f32_16x16x32_bf16(a[mf], b, acc[mf][nf], 0, 0, 0);
    }
  }
  __syncthreads();                 // every wave finished reading h
  store_h(acc, h, wr, wc, l15, l4);
  __syncthreads();                 // h fully rewritten
}

// XSTAGED=true: X A-fragments from global ws (low regs, launch_bounds(512,4)).
// XSTAGED=false: round-4 legacy (xf in registers, launch_bounds(512,2)).
template<bool XSTAGED>
__global__ __launch_bounds__(NTHREADS, XSTAGED ? 4 : 2)
void meganerf_fused(const float* __restrict__ x, const float* __restrict__ cent,
                    const float* __restrict__ b1, const float* __restrict__ b2,
                    const float* __restrict__ b3, const float* __restrict__ bo,
                    const unsigned short* __restrict__ wf,
                    const unsigned short* __restrict__ xs,
                    float* __restrict__ out) {
  __shared__ unsigned short hA[MT * HSTR];     // 67584 B (single buffer)
  __shared__ float wcl[MT * NE];               // 4096 B
  __shared__ float oacc[MT * NOUT];            // 2048 B   -> total 73728 B

  const int tid = threadIdx.x;
  const int lane = tid & 63;
  const int wv = tid >> 6;      // 0..7
  const int wr = wv >> 2;       // row group 0..1 (64 rows each)
  const int wc = wv & 3;        // col group 0..3 (64 cols each)
  const int l15 = lane & 15, l4 = lane >> 4;
  const int row0 = blockIdx.x * MT;

  // --- cluster weights (strict IEEE f32, no contraction: must bit-match np) ---
  if (tid < MT) {
    const int p = row0 + tid;
    float px = x[p*XC + 1], py = x[p*XC + 2];
    float d[NE]; float mind = 3.4e38f;
#pragma unroll
    for (int e = 0; e < NE; ++e) {
      float dx = px - cent[e*3 + 1];
      float dy = py - cent[e*3 + 2];
      d[e] = __fsqrt_rn(__fmul_rn(dx, dx) + __fmul_rn(dy, dy));
      mind = fminf(mind, d[e]);
    }
    float m = 1.5f * mind, s = 0.f, inv[NE];
#pragma unroll
    for (int e = 0; e < NE; ++e) {
      float iv = (d[e] > m) ? 0.f : 1.f / (d[e] + 1e-8f);
      inv[e] = iv; s += iv;
    }
#pragma unroll
    for (int e = 0; e < NE; ++e) wcl[tid*NE + e] = inv[e] / s;
  }
  oacc[tid] = 0.f;   // MT*NOUT == 512 == blockDim

  // --- legacy only: X fragments in registers, reused across all experts ---
  bf16x8 xf[XSTAGED ? 1 : 4][KQ1];
  if constexpr (!XSTAGED) {
    const int rbase = row0 + wr*64;
#pragma unroll
    for (int mf = 0; mf < 4; ++mf) {
      const float* src = x + (size_t)(rbase + mf*16 + l15)*XC + 3;
#pragma unroll
      for (int kq = 0; kq < KQ1; ++kq) {
        int kb = kq*32 + l4*8;
        bf16x8 v;
#pragma unroll
        for (int j = 0; j < 8; ++j) {
          float f = (kb + j < FIN) ? src[kb + j] : 0.f;
          v[j] = (short)f2bf(f);
        }
        xf[mf][kq] = v;
      }
    }
  }
  __syncthreads();

  const unsigned short* fw1 = wf;
  const unsigned short* fw2 = wf + W1_ELEMS;
  const unsigned short* fw3 = fw2 + W2_ELEMS;
  const unsigned short* fwo = fw3 + W2_ELEMS;
  // staged X: fragment base for this wave's row tiles (r16 = row>>4)
  const unsigned short* xsb = xs + ((size_t)(blockIdx.x*8 + wr*4)*KQ1)*512 + lane*8;

  for (int e = 0; e < NE; ++e) {
    // ---- layer 1: X(128x96) @ W1 -> relu -> hA ----
    {
      f32x4 acc[4][4];
#pragma unroll
      for (int nf = 0; nf < 4; ++nf) {
        float bv = b1[e*HD + wc*64 + nf*16 + l15];
#pragma unroll
        for (int mf = 0; mf < 4; ++mf)
          acc[mf][nf] = f32x4{bv, bv, bv, bv};
      }
#pragma unroll
      for (int kq = 0; kq < KQ1; ++kq) {
        bf16x8 a1[4];
#pragma unroll
        for (int mf = 0; mf < 4; ++mf) {
          if constexpr (XSTAGED)
            a1[mf] = *(const bf16x8*)(xsb + (mf*KQ1 + kq)*512);
          else
            a1[mf] = xf[mf][kq];
        }
        const unsigned short* bp = fw1 + (((e*NBH + wc*4)*KQ1 + kq) << 9) + lane*8;
#pragma unroll
        for (int nf = 0; nf < 4; ++nf) {
          bf16x8 b = *(const bf16x8*)(bp + ((nf*KQ1) << 9));
#pragma unroll
          for (int mf = 0; mf < 4; ++mf)
            acc[mf][nf] = __builtin_amdgcn_mfma_f32_16x16x32_bf16(a1[mf], b, acc[mf][nf], 0, 0, 0);
        }
      }
      store_h(acc, hA, wr, wc, l15, l4);
    }
    __syncthreads();

    // ---- layer 2, layer 3: in-place hA ----
    layerH(hA, fw2 + (e << 16), b2 + e*HD, wr, wc, l15, l4, lane);
    layerH(hA, fw3 + (e << 16), b3 + e*HD, wr, wc, l15, l4, lane);

    // ---- layer 4 (OUT=4, padded to 16) + gated accumulation; all 8 waves ----
    {
      f32x4 acc = {0.f, 0.f, 0.f, 0.f};
#pragma unroll
      for (int kq = 0; kq < KQH; ++kq) {
        bf16x8 a = *(const bf16x8*)(hA + (wv*16 + l15)*HSTR + kq*32 + l4*8);
        bf16x8 b = *(const bf16x8*)(fwo + ((e*KQH + kq) << 9) + lane*8);
        acc = __builtin_amdgcn_mfma_f32_16x16x32_bf16(a, b, acc, 0, 0, 0);
      }
      if (l15 < NOUT) {
        float bv = bo[e*NOUT + l15];
#pragma unroll
        for (int j = 0; j < 4; ++j) {
          int row = wv*16 + l4*4 + j;            // each thread owns its slots -> no race
          oacc[row*NOUT + l15] += wcl[row*NE + e] * (acc[j] + bv);
        }
      }
    }
    __syncthreads();   // L4 reads of hA done; next expert's L1 may rewrite hA
  }

  out[(size_t)row0*NOUT + tid] = oacc[tid];      // 512 contiguous f32, coalesced
}

extern "C" void kernel_launch(void* const* d_in, const int* in_sizes, int n_in,
                              void* d_out, int out_size, void* d_ws, size_t ws_size,
                              hipStream_t stream) {
  const float* x    = (const float*)d_in[0];
  const float* cent = (const float*)d_in[1];
  const float* W1   = (const float*)d_in[2];
  const float* b1   = (const float*)d_in[3];
  const float* W2   = (const float*)d_in[4];
  const float* b2   = (const float*)d_in[5];
  const float* W3   = (const float*)d_in[6];
  const float* b3   = (const float*)d_in[7];
  const float* Wo   = (const float*)d_in[8];
  const float* bo   = (const float*)d_in[9];
  float* out = (float*)d_out;
  unsigned short* wsb = (unsigned short*)d_ws;

  const int N = in_sizes[0] / XC;                 // 131072
  const int nfragX = (N/16) * KQ1;                // 24576 fragments
  const size_t wbytes = (size_t)WTOT * 2;         // 2,555,904
  const size_t xbytes = (size_t)nfragX * 512 * 2; // 25,165,824

  convert_weights<<<dim3((WTOT + 255) / 256), dim3(256), 0, stream>>>(W1, W2, W3, Wo, wsb);

  if (ws_size >= wbytes + xbytes) {
    unsigned short* xsb2 = wsb + WTOT;
    convert_x<<<dim3((nfragX*512 + 255) / 256), dim3(256), 0, stream>>>(x, xsb2, nfragX);
    meganerf_fused<true><<<dim3(N / MT), dim3(NTHREADS), 0, stream>>>(
        x, cent, b1, b2, b3, bo, wsb, xsb2, out);
  } else {
    meganerf_fused<false><<<dim3(N / MT), dim3(NTHREADS), 0, stream>>>(
        x, cent, b1, b2, b3, bo, wsb, wsb, out);
  }
}